// Round 10
// baseline (254.865 us; speedup 1.0000x reference)
//
#include <hip/hip_runtime.h>
#include <hip/hip_cooperative_groups.h>
#include <hip/hip_bf16.h>
#include <math.h>

namespace cg = cooperative_groups;

#define N1 512
#define N2 512
#define DIN 1280
#define DD 100
#define HH 20
#define NPIX (N1*N2)
#define PB 57

typedef short bf16x8 __attribute__((ext_vector_type(8)));
typedef float f32x4 __attribute__((ext_vector_type(4)));

// workspace layout in floats
static constexpr size_t WS_PP    = 0;                      // 2*1024*100 = 204800
static constexpr size_t WS_W1T   = 204800;                 // 1280*100 = 128000
static constexpr size_t WS_W2B   = 332800;                 // 224*32 ushort -> pad 4096
static constexpr size_t WS_M     = 336896;                 // 20*512*512 = 5242880
static constexpr size_t WS_CRAW  = WS_M + 5242880;         // 262144
static constexpr size_t WS_STATS = WS_CRAW + 262144;       // 64
static constexpr size_t WS_B     = WS_STATS + 64;          // 57*57

union SMem {
  struct { float sT[32][33]; } p;
  struct { float sA[8][132]; float sC[64][132]; float wred[4][40]; } b;
  struct { float sIn[2][4][38][40]; float sSc[HH]; float sSh[HH]; float wsum[4][2]; } d;
  struct { float sB[PB * PB]; float cm[PB]; float cs[PB]; float r1[4]; float r2[4]; } f;
};

// ===================== cooperative mega-kernel (256 blocks = 1/CU) =====================
__global__ __launch_bounds__(256, 1) void kAll(
    const float* __restrict__ x1, const float* __restrict__ x2,
    const float* __restrict__ W1, const float* __restrict__ b1,
    const float* __restrict__ W2,
    const float* __restrict__ bn1g, const float* __restrict__ bn1b,
    const float* __restrict__ cw,
    const float* __restrict__ bn2g, const float* __restrict__ bn2b,
    const float* __restrict__ gamma,
    float* __restrict__ pp, float* __restrict__ w1t,
    unsigned short* __restrict__ w2b,
    float* __restrict__ m, float* __restrict__ Craw,
    float* __restrict__ stats, float* __restrict__ Bp,
    float* __restrict__ out) {
  cg::grid_group grid = cg::this_grid();
  __shared__ SMem sm;
  const int blk = blockIdx.x;
  const int tid = threadIdx.x;
  const int lane = tid & 63;
  const int wv = tid >> 6;
  const int wvu = __builtin_amdgcn_readfirstlane(wv);

  // ---------------- stage P ----------------
  if (blk < 160) {
    const int bx = blk % 40, by = blk / 40;
    const int tx = tid & 31, ty = tid >> 5;
#pragma unroll
    for (int e = 0; e < 4; ++e) {
      int h = by * 32 + ty + e * 8, k = bx * 32 + tx;
      sm.p.sT[ty + e * 8][tx] = (h < DD) ? W1[(size_t)h * DIN + k] : 0.0f;
    }
    __syncthreads();
#pragma unroll
    for (int e = 0; e < 4; ++e) {
      int k = bx * 32 + ty + e * 8, h = by * 32 + tx;
      if (h < DD) w1t[(size_t)k * DD + h] = sm.p.sT[tx][ty + e * 8];
    }
  } else if (blk < 188) {
    int idx = (blk - 160) * 256 + tid;
    if (blk == 160 && tid < 64) stats[tid] = 0.0f;
    if (idx < 224 * 32) {
      int k = idx >> 5, n = idx & 31;
      float v = (n < HH && k < 200) ? W2[n * 200 + k] : 0.0f;
      __hip_bfloat16 bh = __float2bfloat16(v);
      w2b[idx] = *reinterpret_cast<unsigned short*>(&bh);
    }
  }
  grid.sync();

  // ---------------- stage A: 8 rows/block, kh split (blk = rowgrp*2 + kh) ----------
  {
    const int kh = blk & 1;
    const int r0 = (blk >> 1) * 8 + wvu * 2;   // blk>>1 in 0..127 -> rows 0..1022
    const float* xb = (r0 < N1) ? (x1 + (size_t)r0 * DIN) : (x2 + (size_t)(r0 - N1) * DIN);
    const float* xr0 = xb + kh * 640;
    const float* xr1 = xb + DIN + kh * 640;
#pragma unroll 1
    for (int hl = 0; hl < 2; ++hl) {
      int h = hl * 64 + lane;
      if (h < DD) {
        const float* w1p = w1t + (size_t)kh * 640 * DD + h;
        float a00 = 0.f, a01 = 0.f, a10 = 0.f, a11 = 0.f;
#pragma unroll 8
        for (int k = 0; k < 640; k += 2) {
          float wA = w1p[(size_t)k * DD];
          float wB = w1p[(size_t)(k + 1) * DD];
          a00 = fmaf(wA, xr0[k], a00); a01 = fmaf(wB, xr0[k + 1], a01);
          a10 = fmaf(wA, xr1[k], a10); a11 = fmaf(wB, xr1[k + 1], a11);
        }
        pp[(size_t)kh * 102400 + (size_t)r0 * DD + h] = a00 + a01;
        pp[(size_t)kh * 102400 + (size_t)(r0 + 1) * DD + h] = a10 + a11;
      }
    }
  }
  grid.sync();

  // ---------------- stage B: 2 tiles per block ----------
  {
    const int ln = lane & 15;
    const int q  = lane >> 4;
    const int jj = wv * 16 + ln;

    bf16x8 af[7][2];
#pragma unroll
    for (int ks = 0; ks < 7; ++ks)
#pragma unroll
      for (int t = 0; t < 2; ++t) {
        bf16x8 v;
#pragma unroll
        for (int e = 0; e < 8; ++e)
          v[e] = (short)w2b[(ks * 32 + q * 8 + e) * 32 + ln + 16 * t];
        af[ks][t] = v;
      }
    int dOf[14];
    bool isP[14];
#pragma unroll
    for (int hx = 0; hx < 14; ++hx) {
      int kk = (hx >> 1) * 32 + q * 8 + (hx & 1) * 4;
      isP[hx] = kk >= 100;
      dOf[hx] = isP[hx] ? kk - 100 : kk;
    }

#pragma unroll 1
    for (int t = 0; t < 2; ++t) {
      const int bb = blk + t * 256;
      const int bi = bb >> 3, bj = bb & 7;
      if (t) __syncthreads();
      for (int idx = tid; idx < 72 * 33; idx += 256) {
        int r = idx / 33, d4 = idx % 33;
        float4 v = {0.f, 0.f, 0.f, 0.f};
        if (d4 < 25) {
          size_t row = (r < 8) ? (size_t)(bi * 8 + r) : (size_t)(N1 + bj * 64 + (r - 8));
          const float* base = pp + row * DD;
          float4 a0 = ((const float4*)base)[d4];
          float4 a1 = ((const float4*)(base + 102400))[d4];
          float4 bb4 = ((const float4*)b1)[d4];
          v.x = a0.x + a1.x + bb4.x;
          v.y = a0.y + a1.y + bb4.y;
          v.z = a0.z + a1.z + bb4.z;
          v.w = a0.w + a1.w + bb4.w;
        }
        if (r < 8) *(float4*)&sm.b.sA[r][4 * d4] = v;
        else       *(float4*)&sm.b.sC[r - 8][4 * d4] = v;
      }
      __syncthreads();

      float4 cH[14];
#pragma unroll
      for (int hx = 0; hx < 14; ++hx) cH[hx] = *(const float4*)&sm.b.sC[jj][dOf[hx]];

      float st_s[8], st_q[8];
#pragma unroll
      for (int r = 0; r < 8; ++r) { st_s[r] = 0.f; st_q[r] = 0.f; }

      const int gj = bj * 64 + jj;
#pragma unroll 1
      for (int ii = 0; ii < 8; ++ii) {
        bf16x8 bf[7];
#pragma unroll
        for (int ks = 0; ks < 7; ++ks) {
          float4 a0 = *(const float4*)&sm.b.sA[ii][dOf[2 * ks]];
          float4 a1 = *(const float4*)&sm.b.sA[ii][dOf[2 * ks + 1]];
          float4 c0 = cH[2 * ks], c1 = cH[2 * ks + 1];
          float f0 = isP[2*ks]   ? a0.x * c0.x : fabsf(a0.x - c0.x);
          float f1 = isP[2*ks]   ? a0.y * c0.y : fabsf(a0.y - c0.y);
          float f2 = isP[2*ks]   ? a0.z * c0.z : fabsf(a0.z - c0.z);
          float f3 = isP[2*ks]   ? a0.w * c0.w : fabsf(a0.w - c0.w);
          float f4 = isP[2*ks+1] ? a1.x * c1.x : fabsf(a1.x - c1.x);
          float f5 = isP[2*ks+1] ? a1.y * c1.y : fabsf(a1.y - c1.y);
          float f6 = isP[2*ks+1] ? a1.z * c1.z : fabsf(a1.z - c1.z);
          float f7 = isP[2*ks+1] ? a1.w * c1.w : fabsf(a1.w - c1.w);
          union { bf16x8 v; __hip_bfloat162 h2[4]; } u;
          u.h2[0] = __float22bfloat162_rn(make_float2(f0, f1));
          u.h2[1] = __float22bfloat162_rn(make_float2(f2, f3));
          u.h2[2] = __float22bfloat162_rn(make_float2(f4, f5));
          u.h2[3] = __float22bfloat162_rn(make_float2(f6, f7));
          bf[ks] = u.v;
        }
        f32x4 acc0 = {0.f, 0.f, 0.f, 0.f}, acc1 = {0.f, 0.f, 0.f, 0.f};
#pragma unroll
        for (int ks = 0; ks < 7; ++ks) {
          acc0 = __builtin_amdgcn_mfma_f32_16x16x32_bf16(af[ks][0], bf[ks], acc0, 0, 0, 0);
          acc1 = __builtin_amdgcn_mfma_f32_16x16x32_bf16(af[ks][1], bf[ks], acc1, 0, 0, 0);
        }
        const size_t pix = (size_t)(bi * 8 + ii) * N2 + gj;
#pragma unroll
        for (int r = 0; r < 4; ++r) {
          m[(size_t)(4 * q + r) * NPIX + pix] = acc0[r];
          st_s[r] += acc0[r];
          st_q[r] += acc0[r] * acc0[r];
        }
        if (q == 0) {
#pragma unroll
          for (int r = 0; r < 4; ++r)
            m[(size_t)(16 + r) * NPIX + pix] = acc1[r];
        }
#pragma unroll
        for (int r = 0; r < 4; ++r) {
          st_s[4 + r] += acc1[r];
          st_q[4 + r] += acc1[r] * acc1[r];
        }
      }
#pragma unroll
      for (int r = 0; r < 8; ++r) {
#pragma unroll
        for (int off = 1; off < 16; off <<= 1) {
          st_s[r] += __shfl_xor(st_s[r], off);
          st_q[r] += __shfl_xor(st_q[r], off);
        }
      }
      if (ln == 0) {
#pragma unroll
        for (int r = 0; r < 4; ++r) {
          sm.b.wred[wv][4 * q + r]      = st_s[r];
          sm.b.wred[wv][20 + 4 * q + r] = st_q[r];
        }
        if (q == 0) {
#pragma unroll
          for (int r = 0; r < 4; ++r) {
            sm.b.wred[wv][16 + r] = st_s[4 + r];
            sm.b.wred[wv][36 + r] = st_q[4 + r];
          }
        }
      }
      __syncthreads();
      if (tid < 40)
        atomicAdd(&stats[tid],
                  sm.b.wred[0][tid] + sm.b.wred[1][tid] + sm.b.wred[2][tid] + sm.b.wred[3][tid]);
    }
  }
  grid.sync();

  // ---------------- stage D: conv 7x7, 20ch, dbuf -> Craw + BN2 stats ----------
  {
    if (tid < HH) {
      float s = stats[tid], q = stats[HH + tid];
      float mu = s * (1.0f / NPIX);
      float var = q * (1.0f / NPIX) - mu * mu;
      float g = bn1g[tid] / sqrtf(var + 1e-5f);
      sm.d.sSc[tid] = g;
      sm.d.sSh[tid] = bn1b[tid] - mu * g;
    }
    const int by = (blk >> 4) * 32, bx = (blk & 15) * 32;
    const int gxs = bx + lane - 4;
    const bool colOk = (lane < 40) && (gxs >= 0) && (gxs < N2);
    float ld[38];
    {
      const float* mp = m + (size_t)wvu * NPIX + gxs;
#pragma unroll
      for (int r = 0; r < 38; ++r) {
        int gy = by + r - 3;
        ld[r] = (colOk && gy >= 0 && gy < N1) ? mp[(size_t)gy * N2] : 0.0f;
      }
    }
    __syncthreads();
    if (lane < 40) {
      float sc = sm.d.sSc[wvu], sh = sm.d.sSh[wvu];
#pragma unroll
      for (int r = 0; r < 38; ++r)
        sm.d.sIn[0][wvu][r][lane] = fmaxf(fmaf(ld[r], sc, sh), 0.0f) * (ld[r] != 0.0f || true ? 1.0f : 0.0f);
    }
    // note: out-of-range cells had ld=0 -> relu(sh) could be nonzero; must force 0:
    if (lane < 40) {
#pragma unroll
      for (int r = 0; r < 38; ++r) {
        int gy = by + r - 3;
        bool ok = colOk && gy >= 0 && gy < N1;
        if (!ok) sm.d.sIn[0][wvu][r][lane] = 0.0f;
      }
    }
    __syncthreads();
    const int ty = tid >> 4, tx = tid & 15;
    float acc00 = 0.f, acc01 = 0.f, acc10 = 0.f, acc11 = 0.f;
#pragma unroll 1
    for (int cc = 0; cc < 5; ++cc) {
      if (cc < 4) {
        const float* mp = m + (size_t)((cc + 1) * 4 + wvu) * NPIX + gxs;
#pragma unroll
        for (int r = 0; r < 38; ++r) {
          int gy = by + r - 3;
          ld[r] = (colOk && gy >= 0 && gy < N1) ? mp[(size_t)gy * N2] : 0.0f;
        }
      }
      const int cur = cc & 1;
#pragma unroll 1
      for (int ch4 = 0; ch4 < 4; ++ch4) {
        float2 win[8][5];
#pragma unroll
        for (int rr = 0; rr < 8; ++rr)
#pragma unroll
          for (int qq = 0; qq < 5; ++qq)
            win[rr][qq] = *(const float2*)&sm.d.sIn[cur][ch4][2 * ty + rr][2 * tx + 2 * qq];
        const float* wch = cw + (cc * 4 + ch4) * 49;   // uniform -> s_load
#pragma unroll
        for (int ky = 0; ky < 7; ++ky)
#pragma unroll
          for (int kx = 0; kx < 7; ++kx) {
            float wt = wch[ky * 7 + kx];
            float e0 = ((kx + 1) & 1) ? win[ky][(kx + 1) >> 1].y : win[ky][(kx + 1) >> 1].x;
            float e1 = ((kx + 2) & 1) ? win[ky][(kx + 2) >> 1].y : win[ky][(kx + 2) >> 1].x;
            float f0 = ((kx + 1) & 1) ? win[ky + 1][(kx + 1) >> 1].y : win[ky + 1][(kx + 1) >> 1].x;
            float f1 = ((kx + 2) & 1) ? win[ky + 1][(kx + 2) >> 1].y : win[ky + 1][(kx + 2) >> 1].x;
            acc00 = fmaf(e0, wt, acc00);
            acc01 = fmaf(e1, wt, acc01);
            acc10 = fmaf(f0, wt, acc10);
            acc11 = fmaf(f1, wt, acc11);
          }
      }
      __syncthreads();
      if (cc < 4 && lane < 40) {
        int ch = (cc + 1) * 4 + wvu;
        float sc = sm.d.sSc[ch], sh = sm.d.sSh[ch];
#pragma unroll
        for (int r = 0; r < 38; ++r) {
          int gy = by + r - 3;
          bool ok = colOk && gy >= 0 && gy < N1;
          sm.d.sIn[cur ^ 1][wvu][r][lane] = ok ? fmaxf(fmaf(ld[r], sc, sh), 0.0f) : 0.0f;
        }
      }
      __syncthreads();
    }
    const int oy = by + 2 * ty, ox = bx + 2 * tx;
    float2 r0 = {acc00, acc01}, r1 = {acc10, acc11};
    *(float2*)&Craw[(size_t)oy * N2 + ox] = r0;
    *(float2*)&Craw[(size_t)(oy + 1) * N2 + ox] = r1;
    float s = acc00 + acc01 + acc10 + acc11;
    float q = acc00 * acc00 + acc01 * acc01 + acc10 * acc10 + acc11 * acc11;
#pragma unroll
    for (int off = 32; off; off >>= 1) {
      s += __shfl_xor(s, off);
      q += __shfl_xor(q, off);
    }
    if (lane == 0) { sm.d.wsum[wv][0] = s; sm.d.wsum[wv][1] = q; }
    __syncthreads();
    if (tid < 2) {
      float v = sm.d.wsum[0][tid] + sm.d.wsum[1][tid] + sm.d.wsum[2][tid] + sm.d.wsum[3][tid];
      atomicAdd(&stats[2 * HH + tid], v);
    }
  }
  grid.sync();

  // ---------------- stage E2M ----------
  {
    float s = stats[2 * HH], q = stats[2 * HH + 1];
    float mu = s * (1.0f / NPIX);
    float var = q * (1.0f / NPIX) - mu * mu;
    float g = bn2g[0] / sqrtf(var + 1e-5f);
    float b = bn2b[0] - mu * g;
    float* Cout = out + 1;
    for (int w = blk * 4 + wv; w < PB * PB; w += 1024) {
      const int wy = w / PB, wx = w % PB;
      const int y0 = wy * 9 - 4, x0 = wx * 9 - 4;
      float mx = -1e30f;
      for (int e = lane; e < 144; e += 64) {
        int dy = e / 12, dx = e % 12;
        int y = y0 + dy, x = x0 + dx;
        bool inWin = (dy < 9) && (dx < 9);
        bool claim = (y >= 0) && (y < N1) && (x >= 0) && (x < N2) &&
                     (dy < 9 || wy == PB - 1) && (dx < 9 || wx == PB - 1);
        if (claim) {
          float z = Craw[(size_t)y * N2 + x] * g + b;
          float sg = 1.0f / (1.0f + expf(-z));
          Cout[(size_t)y * N2 + x] = sg;
          if (inWin) mx = fmaxf(mx, sg);
        }
      }
#pragma unroll
      for (int off = 32; off; off >>= 1) mx = fmaxf(mx, __shfl_xor(mx, off));
      if (lane == 0) Bp[w] = mx;
    }
  }
  grid.sync();

  // ---------------- stage F ----------
  if (blk == 0) {
    for (int i = tid; i < PB * PB; i += 256) sm.f.sB[i] = Bp[i];
    __syncthreads();
    if (tid < PB) {
      float s = 0.0f;
      for (int h = 0; h < PB; ++h) s += sm.f.sB[h * PB + tid];
      float mean = s / (float)PB;
      float v = 0.0f;
      for (int h = 0; h < PB; ++h) { float d = sm.f.sB[h * PB + tid] - mean; v += d * d; }
      sm.f.cm[tid] = mean;
      sm.f.cs[tid] = sqrtf(v / (float)(PB - 1) + 1e-5f);
    }
    __syncthreads();
    const float g = gamma[0];
    float sq = 0.0f, cnt = 0.0f;
    for (int i = tid; i < PB * PB; i += 256) {
      int w = i % PB;
      float qv = sm.f.sB[i] - sm.f.cm[w] - g * sm.f.cs[w];
      if (qv > 0.0f) { sq += qv; cnt += 1.0f; }
    }
#pragma unroll
    for (int off = 32; off; off >>= 1) {
      sq += __shfl_xor(sq, off);
      cnt += __shfl_xor(cnt, off);
    }
    if (lane == 0) { sm.f.r1[wv] = sq; sm.f.r2[wv] = cnt; }
    __syncthreads();
    if (tid == 0) {
      float S = sm.f.r1[0] + sm.f.r1[1] + sm.f.r1[2] + sm.f.r1[3];
      float Cn = sm.f.r2[0] + sm.f.r2[1] + sm.f.r2[2] + sm.f.r2[3];
      float phat = S / (Cn + 1.0f);
      float sig = 1.0f / (1.0f + expf(-phat));
      out[0] = fminf(fmaxf(sig, 0.0f), 1.0f);
    }
  }
}

// ===================== fallback path: proven R8 kernels =====================
__global__ __launch_bounds__(256) void kP(const float* __restrict__ W1,
                                          const float* __restrict__ W2,
                                          float* __restrict__ w1t,
                                          unsigned short* __restrict__ w2b,
                                          float* __restrict__ stats) {
  const int tid = threadIdx.x;
  if (blockIdx.x >= 160) {
    int idx = (blockIdx.x - 160) * 256 + tid;
    if (blockIdx.x == 160 && tid < 64) stats[tid] = 0.0f;
    if (idx < 224 * 32) {
      int k = idx >> 5, n = idx & 31;
      float v = (n < HH && k < 200) ? W2[n * 200 + k] : 0.0f;
      __hip_bfloat16 b = __float2bfloat16(v);
      w2b[idx] = *reinterpret_cast<unsigned short*>(&b);
    }
    return;
  }
  __shared__ float sT[32][33];
  const int bx = blockIdx.x % 40, by = blockIdx.x / 40;
  const int tx = tid & 31, ty = tid >> 5;
#pragma unroll
  for (int e = 0; e < 4; ++e) {
    int h = by * 32 + ty + e * 8, k = bx * 32 + tx;
    sT[ty + e * 8][tx] = (h < DD) ? W1[(size_t)h * DIN + k] : 0.0f;
  }
  __syncthreads();
#pragma unroll
  for (int e = 0; e < 4; ++e) {
    int k = bx * 32 + ty + e * 8, h = by * 32 + tx;
    if (h < DD) w1t[(size_t)k * DD + h] = sT[tx][ty + e * 8];
  }
}

__global__ __launch_bounds__(512) void kA(const float* __restrict__ x1,
                                          const float* __restrict__ x2,
                                          const float* __restrict__ w1t,
                                          float* __restrict__ pp) {
  const int tid = threadIdx.x;
  const int w  = __builtin_amdgcn_readfirstlane(tid >> 6);
  const int rp = w >> 1, hh = w & 1;
  const int h = hh * 64 + (tid & 63);
  if (h >= DD) return;
  const int kh = blockIdx.x & 1;
  const int r0 = (blockIdx.x >> 1) * 8 + rp * 2;
  const float* xb = (r0 < N1) ? (x1 + (size_t)r0 * DIN) : (x2 + (size_t)(r0 - N1) * DIN);
  const float* xr0 = xb + kh * 640;
  const float* xr1 = xb + DIN + kh * 640;
  const float* w1p = w1t + (size_t)kh * 640 * DD + h;
  float a00 = 0.f, a01 = 0.f, a10 = 0.f, a11 = 0.f;
#pragma unroll 8
  for (int k = 0; k < 640; k += 2) {
    float wA = w1p[(size_t)k * DD];
    float wB = w1p[(size_t)(k + 1) * DD];
    a00 = fmaf(wA, xr0[k], a00); a01 = fmaf(wB, xr0[k + 1], a01);
    a10 = fmaf(wA, xr1[k], a10); a11 = fmaf(wB, xr1[k + 1], a11);
  }
  pp[(size_t)kh * 102400 + (size_t)r0 * DD + h] = a00 + a01;
  pp[(size_t)kh * 102400 + (size_t)(r0 + 1) * DD + h] = a10 + a11;
}

__global__ __launch_bounds__(256, 2) void kB(const float* __restrict__ pp,
                                             const float* __restrict__ b1,
                                             const unsigned short* __restrict__ w2b,
                                             float* __restrict__ m,
                                             float* __restrict__ stats) {
  __shared__ float sA[8][132];
  __shared__ float sC[64][132];
  __shared__ float wred[4][40];
  const int tid = threadIdx.x;
  const int bi = blockIdx.x >> 3, bj = blockIdx.x & 7;
  for (int idx = tid; idx < 72 * 33; idx += 256) {
    int r = idx / 33, d4 = idx % 33;
    float4 v = {0.f, 0.f, 0.f, 0.f};
    if (d4 < 25) {
      size_t row = (r < 8) ? (size_t)(bi * 8 + r) : (size_t)(N1 + bj * 64 + (r - 8));
      const float* base = pp + row * DD;
      float4 a0 = ((const float4*)base)[d4];
      float4 a1 = ((const float4*)(base + 102400))[d4];
      float4 bb = ((const float4*)b1)[d4];
      v.x = a0.x + a1.x + bb.x;
      v.y = a0.y + a1.y + bb.y;
      v.z = a0.z + a1.z + bb.z;
      v.w = a0.w + a1.w + bb.w;
    }
    if (r < 8) *(float4*)&sA[r][4 * d4] = v;
    else       *(float4*)&sC[r - 8][4 * d4] = v;
  }
  __syncthreads();
  const int w = tid >> 6, lane = tid & 63;
  const int ln = lane & 15, q = lane >> 4;
  const int jj = w * 16 + ln;
  bf16x8 af[7][2];
#pragma unroll
  for (int ks = 0; ks < 7; ++ks)
#pragma unroll
    for (int t = 0; t < 2; ++t) {
      bf16x8 v;
#pragma unroll
      for (int e = 0; e < 8; ++e)
        v[e] = (short)w2b[(ks * 32 + q * 8 + e) * 32 + ln + 16 * t];
      af[ks][t] = v;
    }
  int dOf[14];
  bool isP[14];
  float4 cH[14];
#pragma unroll
  for (int hx = 0; hx < 14; ++hx) {
    int kk = (hx >> 1) * 32 + q * 8 + (hx & 1) * 4;
    isP[hx] = kk >= 100;
    dOf[hx] = isP[hx] ? kk - 100 : kk;
    cH[hx] = *(const float4*)&sC[jj][dOf[hx]];
  }
  float st_s[8], st_q[8];
#pragma unroll
  for (int r = 0; r < 8; ++r) { st_s[r] = 0.f; st_q[r] = 0.f; }
  const int gj = bj * 64 + jj;
#pragma unroll 1
  for (int ii = 0; ii < 8; ++ii) {
    bf16x8 bf[7];
#pragma unroll
    for (int ks = 0; ks < 7; ++ks) {
      float4 a0 = *(const float4*)&sA[ii][dOf[2 * ks]];
      float4 a1 = *(const float4*)&sA[ii][dOf[2 * ks + 1]];
      float4 c0 = cH[2 * ks], c1 = cH[2 * ks + 1];
      float f0 = isP[2*ks]   ? a0.x * c0.x : fabsf(a0.x - c0.x);
      float f1 = isP[2*ks]   ? a0.y * c0.y : fabsf(a0.y - c0.y);
      float f2 = isP[2*ks]   ? a0.z * c0.z : fabsf(a0.z - c0.z);
      float f3 = isP[2*ks]   ? a0.w * c0.w : fabsf(a0.w - c0.w);
      float f4 = isP[2*ks+1] ? a1.x * c1.x : fabsf(a1.x - c1.x);
      float f5 = isP[2*ks+1] ? a1.y * c1.y : fabsf(a1.y - c1.y);
      float f6 = isP[2*ks+1] ? a1.z * c1.z : fabsf(a1.z - c1.z);
      float f7 = isP[2*ks+1] ? a1.w * c1.w : fabsf(a1.w - c1.w);
      union { bf16x8 v; __hip_bfloat162 h2[4]; } u;
      u.h2[0] = __float22bfloat162_rn(make_float2(f0, f1));
      u.h2[1] = __float22bfloat162_rn(make_float2(f2, f3));
      u.h2[2] = __float22bfloat162_rn(make_float2(f4, f5));
      u.h2[3] = __float22bfloat162_rn(make_float2(f6, f7));
      bf[ks] = u.v;
    }
    f32x4 acc0 = {0.f, 0.f, 0.f, 0.f}, acc1 = {0.f, 0.f, 0.f, 0.f};
#pragma unroll
    for (int ks = 0; ks < 7; ++ks) {
      acc0 = __builtin_amdgcn_mfma_f32_16x16x32_bf16(af[ks][0], bf[ks], acc0, 0, 0, 0);
      acc1 = __builtin_amdgcn_mfma_f32_16x16x32_bf16(af[ks][1], bf[ks], acc1, 0, 0, 0);
    }
    const size_t pix = (size_t)(bi * 8 + ii) * N2 + gj;
#pragma unroll
    for (int r = 0; r < 4; ++r) {
      m[(size_t)(4 * q + r) * NPIX + pix] = acc0[r];
      st_s[r] += acc0[r];
      st_q[r] += acc0[r] * acc0[r];
    }
    if (q == 0) {
#pragma unroll
      for (int r = 0; r < 4; ++r)
        m[(size_t)(16 + r) * NPIX + pix] = acc1[r];
    }
#pragma unroll
    for (int r = 0; r < 4; ++r) {
      st_s[4 + r] += acc1[r];
      st_q[4 + r] += acc1[r] * acc1[r];
    }
  }
#pragma unroll
  for (int r = 0; r < 8; ++r) {
#pragma unroll
    for (int off = 1; off < 16; off <<= 1) {
      st_s[r] += __shfl_xor(st_s[r], off);
      st_q[r] += __shfl_xor(st_q[r], off);
    }
  }
  if (ln == 0) {
#pragma unroll
    for (int r = 0; r < 4; ++r) {
      wred[w][4 * q + r]      = st_s[r];
      wred[w][20 + 4 * q + r] = st_q[r];
    }
    if (q == 0) {
#pragma unroll
      for (int r = 0; r < 4; ++r) {
        wred[w][16 + r] = st_s[4 + r];
        wred[w][36 + r] = st_q[4 + r];
      }
    }
  }
  __syncthreads();
  if (tid < 40)
    atomicAdd(&stats[tid], wred[0][tid] + wred[1][tid] + wred[2][tid] + wred[3][tid]);
}

__global__ __launch_bounds__(256, 1) void kD(const float* __restrict__ m,
                                             const float* __restrict__ bn1g,
                                             const float* __restrict__ bn1b,
                                             const float* __restrict__ cw,
                                             float* __restrict__ stats,
                                             float* __restrict__ Craw) {
  __shared__ float sIn[2][4][38][40];
  __shared__ float sSc[HH], sSh[HH];
  __shared__ float wsum[4][2];
  const int tid = threadIdx.x;
  if (tid < HH) {
    float s = stats[tid], q = stats[HH + tid];
    float mu = s * (1.0f / NPIX);
    float var = q * (1.0f / NPIX) - mu * mu;
    float g = bn1g[tid] / sqrtf(var + 1e-5f);
    sSc[tid] = g;
    sSh[tid] = bn1b[tid] - mu * g;
  }
  const int by = (blockIdx.x >> 4) * 32, bx = (blockIdx.x & 15) * 32;
  const int w = tid >> 6, lane = tid & 63;
  const int gxs = bx + lane - 4;
  const bool colOk = (lane < 40) && (gxs >= 0) && (gxs < N2);
  float ld[38];
  {
    const float* mp = m + (size_t)w * NPIX + gxs;
#pragma unroll
    for (int r = 0; r < 38; ++r) {
      int gy = by + r - 3;
      ld[r] = (colOk && gy >= 0 && gy < N1) ? mp[(size_t)gy * N2] : 0.0f;
    }
  }
  __syncthreads();
  if (lane < 40) {
    float sc = sSc[w], sh = sSh[w];
#pragma unroll
    for (int r = 0; r < 38; ++r) {
      int gy = by + r - 3;
      bool ok = colOk && gy >= 0 && gy < N1;
      sIn[0][w][r][lane] = ok ? fmaxf(fmaf(ld[r], sc, sh), 0.0f) : 0.0f;
    }
  }
  __syncthreads();
  const int ty = tid >> 4, tx = tid & 15;
  float acc00 = 0.f, acc01 = 0.f, acc10 = 0.f, acc11 = 0.f;
#pragma unroll 1
  for (int cc = 0; cc < 5; ++cc) {
    if (cc < 4) {
      const float* mp = m + (size_t)((cc + 1) * 4 + w) * NPIX + gxs;
#pragma unroll
      for (int r = 0; r < 38; ++r) {
        int gy = by + r - 3;
        ld[r] = (colOk && gy >= 0 && gy < N1) ? mp[(size_t)gy * N2] : 0.0f;
      }
    }
    const int cur = cc & 1;
#pragma unroll 1
    for (int ch4 = 0; ch4 < 4; ++ch4) {
      float2 win[8][5];
#pragma unroll
      for (int rr = 0; rr < 8; ++rr)
#pragma unroll
        for (int qq = 0; qq < 5; ++qq)
          win[rr][qq] = *(const float2*)&sIn[cur][ch4][2 * ty + rr][2 * tx + 2 * qq];
      const float* wch = cw + (cc * 4 + ch4) * 49;
#pragma unroll
      for (int ky = 0; ky < 7; ++ky)
#pragma unroll
        for (int kx = 0; kx < 7; ++kx) {
          float wt = wch[ky * 7 + kx];
          float e0 = ((kx + 1) & 1) ? win[ky][(kx + 1) >> 1].y : win[ky][(kx + 1) >> 1].x;
          float e1 = ((kx + 2) & 1) ? win[ky][(kx + 2) >> 1].y : win[ky][(kx + 2) >> 1].x;
          float f0 = ((kx + 1) & 1) ? win[ky + 1][(kx + 1) >> 1].y : win[ky + 1][(kx + 1) >> 1].x;
          float f1 = ((kx + 2) & 1) ? win[ky + 1][(kx + 2) >> 1].y : win[ky + 1][(kx + 2) >> 1].x;
          acc00 = fmaf(e0, wt, acc00);
          acc01 = fmaf(e1, wt, acc01);
          acc10 = fmaf(f0, wt, acc10);
          acc11 = fmaf(f1, wt, acc11);
        }
    }
    __syncthreads();
    if (cc < 4 && lane < 40) {
      int ch = (cc + 1) * 4 + w;
      float sc = sSc[ch], sh = sSh[ch];
#pragma unroll
      for (int r = 0; r < 38; ++r) {
        int gy = by + r - 3;
        bool ok = colOk && gy >= 0 && gy < N1;
        sIn[cur ^ 1][w][r][lane] = ok ? fmaxf(fmaf(ld[r], sc, sh), 0.0f) : 0.0f;
      }
    }
    __syncthreads();
  }
  const int oy = by + 2 * ty, ox = bx + 2 * tx;
  float2 r0 = {acc00, acc01}, r1 = {acc10, acc11};
  *(float2*)&Craw[(size_t)oy * N2 + ox] = r0;
  *(float2*)&Craw[(size_t)(oy + 1) * N2 + ox] = r1;
  float s = acc00 + acc01 + acc10 + acc11;
  float q = acc00 * acc00 + acc01 * acc01 + acc10 * acc10 + acc11 * acc11;
#pragma unroll
  for (int off = 32; off; off >>= 1) {
    s += __shfl_xor(s, off);
    q += __shfl_xor(q, off);
  }
  if (lane == 0) { wsum[w][0] = s; wsum[w][1] = q; }
  __syncthreads();
  if (tid < 2) {
    float v = wsum[0][tid] + wsum[1][tid] + wsum[2][tid] + wsum[3][tid];
    atomicAdd(&stats[2 * HH + tid], v);
  }
}

__global__ __launch_bounds__(256) void kE2M(const float* __restrict__ Craw,
                                            const float* __restrict__ stats,
                                            const float* __restrict__ bn2g,
                                            const float* __restrict__ bn2b,
                                            float* __restrict__ Cout,
                                            float* __restrict__ B) {
  const int w = blockIdx.x * 4 + (threadIdx.x >> 6);
  const int lane = threadIdx.x & 63;
  float s = stats[2 * HH], q = stats[2 * HH + 1];
  float mu = s * (1.0f / NPIX);
  float var = q * (1.0f / NPIX) - mu * mu;
  float g = bn2g[0] / sqrtf(var + 1e-5f);
  float b = bn2b[0] - mu * g;
  if (w >= PB * PB) return;
  const int wy = w / PB, wx = w % PB;
  const int y0 = wy * 9 - 4, x0 = wx * 9 - 4;
  float mx = -1e30f;
  for (int e = lane; e < 144; e += 64) {
    int dy = e / 12, dx = e % 12;
    int y = y0 + dy, x = x0 + dx;
    bool inWin = (dy < 9) && (dx < 9);
    bool claim = (y >= 0) && (y < N1) && (x >= 0) && (x < N2) &&
                 (dy < 9 || wy == PB - 1) && (dx < 9 || wx == PB - 1);
    if (claim) {
      float z = Craw[(size_t)y * N2 + x] * g + b;
      float sg = 1.0f / (1.0f + expf(-z));
      Cout[(size_t)y * N2 + x] = sg;
      if (inWin) mx = fmaxf(mx, sg);
    }
  }
#pragma unroll
  for (int off = 32; off; off >>= 1) mx = fmaxf(mx, __shfl_xor(mx, off));
  if (lane == 0) B[w] = mx;
}

__global__ __launch_bounds__(1024) void kF(const float* __restrict__ B,
                                           const float* __restrict__ gamma,
                                           float* __restrict__ out0) {
  __shared__ float sB[PB * PB];
  __shared__ float cm[PB], cs[PB];
  __shared__ float r1[16], r2[16];
  const int tid = threadIdx.x;
  for (int i = tid; i < PB * PB; i += 1024) sB[i] = B[i];
  __syncthreads();
  if (tid < PB * 16) {
    int c = tid >> 4, g = tid & 15;
    float s = 0.0f;
    for (int h = g; h < PB; h += 16) s += sB[h * PB + c];
#pragma unroll
    for (int off = 1; off < 16; off <<= 1) s += __shfl_xor(s, off);
    float mean = s / (float)PB;
    float v = 0.0f;
    for (int h = g; h < PB; h += 16) { float d = sB[h * PB + c] - mean; v += d * d; }
#pragma unroll
    for (int off = 1; off < 16; off <<= 1) v += __shfl_xor(v, off);
    if (g == 0) {
      cm[c] = mean;
      cs[c] = sqrtf(v / (float)(PB - 1) + 1e-5f);
    }
  }
  __syncthreads();
  const float g = gamma[0];
  float sq = 0.0f, cnt = 0.0f;
  for (int i = tid; i < PB * PB; i += 1024) {
    int w = i % PB;
    float qv = sB[i] - cm[w] - g * cs[w];
    if (qv > 0.0f) { sq += qv; cnt += 1.0f; }
  }
#pragma unroll
  for (int off = 32; off; off >>= 1) {
    sq += __shfl_xor(sq, off);
    cnt += __shfl_xor(cnt, off);
  }
  if ((tid & 63) == 0) { r1[tid >> 6] = sq; r2[tid >> 6] = cnt; }
  __syncthreads();
  if (tid == 0) {
    float S = 0.f, Cn = 0.f;
#pragma unroll
    for (int e = 0; e < 16; ++e) { S += r1[e]; Cn += r2[e]; }
    float phat = S / (Cn + 1.0f);
    float sig = 1.0f / (1.0f + expf(-phat));
    out0[0] = fminf(fmaxf(sig, 0.0f), 1.0f);
  }
}

extern "C" void kernel_launch(void* const* d_in, const int* in_sizes, int n_in,
                              void* d_out, int out_size, void* d_ws, size_t ws_size,
                              hipStream_t stream) {
  const float* x1    = (const float*)d_in[0];
  const float* x2    = (const float*)d_in[1];
  const float* W1    = (const float*)d_in[2];
  const float* b1    = (const float*)d_in[3];
  const float* W2    = (const float*)d_in[4];
  const float* bn1g  = (const float*)d_in[6];
  const float* bn1b  = (const float*)d_in[7];
  const float* convw = (const float*)d_in[8];
  const float* bn2g  = (const float*)d_in[10];
  const float* bn2b  = (const float*)d_in[11];
  const float* gamma = (const float*)d_in[12];

  float* ws    = (float*)d_ws;
  float* pp    = ws + WS_PP;
  float* w1t   = ws + WS_W1T;
  unsigned short* w2b = (unsigned short*)(ws + WS_W2B);
  float* m     = ws + WS_M;
  float* Craw  = ws + WS_CRAW;
  float* stats = ws + WS_STATS;
  float* Bp    = ws + WS_B;
  float* out   = (float*)d_out;

  void* args[] = {
    (void*)&x1, (void*)&x2, (void*)&W1, (void*)&b1, (void*)&W2,
    (void*)&bn1g, (void*)&bn1b, (void*)&convw, (void*)&bn2g, (void*)&bn2b,
    (void*)&gamma,
    (void*)&pp, (void*)&w1t, (void*)&w2b, (void*)&m, (void*)&Craw,
    (void*)&stats, (void*)&Bp, (void*)&out
  };
  hipError_t e = hipLaunchCooperativeKernel((void*)kAll, dim3(256), dim3(256),
                                            args, 0, stream);
  if (e != hipSuccess) {
    // fallback: proven multi-kernel path
    kP<<<188, 256, 0, stream>>>(W1, W2, w1t, w2b, stats);
    kA<<<256, 512, 0, stream>>>(x1, x2, w1t, pp);
    kB<<<512, 256, 0, stream>>>(pp, b1, w2b, m, stats);
    kD<<<256, 256, 0, stream>>>(m, bn1g, bn1b, convw, stats, Craw);
    kE2M<<<(PB * PB + 3) / 4, 256, 0, stream>>>(Craw, stats, bn2g, bn2b, out + 1, Bp);
    kF<<<1, 1024, 0, stream>>>(Bp, gamma, out);
  }
}

// Round 11
// 92.169 us; speedup vs baseline: 2.7652x; 2.7652x over previous
//
#include <hip/hip_runtime.h>
#include <hip/hip_bf16.h>
#include <math.h>

#define N1 512
#define N2 512
#define DIN 1280
#define DD 100
#define HH 20
#define NPIX (N1*N2)
#define PB 57

typedef short bf16x8 __attribute__((ext_vector_type(8)));
typedef float f32x4 __attribute__((ext_vector_type(4)));

// workspace layout in floats
static constexpr size_t WS_PP    = 0;                      // 4*1024*100 = 409600
static constexpr size_t WS_W1T   = 409600;                 // 1280*100 = 128000
static constexpr size_t WS_W2B   = 537600;                 // 224*32 ushort -> pad 4096
static constexpr size_t WS_M     = 541696;                 // 20*512*512 = 5242880
static constexpr size_t WS_CRAW  = WS_M + 5242880;         // 262144
static constexpr size_t WS_STATS = WS_CRAW + 262144;       // 64
static constexpr size_t WS_B     = WS_STATS + 64;          // 57*57

// ---- prologue: transpose W1 -> w1t[k][h], build bf16 W2^T [224][32], zero stats
__global__ __launch_bounds__(256) void kP(const float* __restrict__ W1,
                                          const float* __restrict__ W2,
                                          float* __restrict__ w1t,
                                          unsigned short* __restrict__ w2b,
                                          float* __restrict__ stats) {
  const int tid = threadIdx.x;
  if (blockIdx.x >= 160) {
    int idx = (blockIdx.x - 160) * 256 + tid;
    if (blockIdx.x == 160 && tid < 64) stats[tid] = 0.0f;
    if (idx < 224 * 32) {
      int k = idx >> 5, n = idx & 31;
      float v = (n < HH && k < 200) ? W2[n * 200 + k] : 0.0f;
      __hip_bfloat16 b = __float2bfloat16(v);
      w2b[idx] = *reinterpret_cast<unsigned short*>(&b);
    }
    return;
  }
  __shared__ float sT[32][33];
  const int bx = blockIdx.x % 40, by = blockIdx.x / 40;
  const int tx = tid & 31, ty = tid >> 5;
#pragma unroll
  for (int e = 0; e < 4; ++e) {
    int h = by * 32 + ty + e * 8, k = bx * 32 + tx;
    sT[ty + e * 8][tx] = (h < DD) ? W1[(size_t)h * DIN + k] : 0.0f;
  }
  __syncthreads();
#pragma unroll
  for (int e = 0; e < 4; ++e) {
    int k = bx * 32 + ty + e * 8, h = by * 32 + tx;
    if (h < DD) w1t[(size_t)k * DD + h] = sT[tx][ty + e * 8];
  }
}

// ---- projection partials: 4-way K split (K=320 each), 4 rows/block
// 1024 blocks x 256 thr = 4 waves/SIMD machine-wide
__global__ __launch_bounds__(256) void kA(const float* __restrict__ x1,
                                          const float* __restrict__ x2,
                                          const float* __restrict__ w1t,
                                          float* __restrict__ pp) {
  const int tid = threadIdx.x;
  const int w  = __builtin_amdgcn_readfirstlane(tid >> 6);  // wave 0..3
  const int rp = w >> 1, hh = w & 1;
  const int h = hh * 64 + (tid & 63);
  if (h >= DD) return;
  const int kq = blockIdx.x & 3;
  const int r0 = (blockIdx.x >> 2) * 4 + rp * 2;
  const float* xb = (r0 < N1) ? (x1 + (size_t)r0 * DIN) : (x2 + (size_t)(r0 - N1) * DIN);
  const float* xr0 = xb + kq * 320;
  const float* xr1 = xb + DIN + kq * 320;
  const float* w1p = w1t + (size_t)kq * 320 * DD + h;
  float a00 = 0.f, a01 = 0.f, a10 = 0.f, a11 = 0.f;
#pragma unroll 8
  for (int k = 0; k < 320; k += 2) {
    float wA = w1p[(size_t)k * DD];
    float wB = w1p[(size_t)(k + 1) * DD];
    a00 = fmaf(wA, xr0[k], a00); a01 = fmaf(wB, xr0[k + 1], a01);
    a10 = fmaf(wA, xr1[k], a10); a11 = fmaf(wB, xr1[k + 1], a11);
  }
  pp[(size_t)kq * 102400 + (size_t)r0 * DD + h] = a00 + a01;
  pp[(size_t)kq * 102400 + (size_t)(r0 + 1) * DD + h] = a10 + a11;
}

// ---- pairwise features + FC2 via MFMA bf16 + BN1 stats (R8 core, 4-partial staging)
__global__ __launch_bounds__(256, 2) void kB(const float* __restrict__ pp,
                                             const float* __restrict__ b1,
                                             const unsigned short* __restrict__ w2b,
                                             float* __restrict__ m,
                                             float* __restrict__ stats) {
  __shared__ float sA[8][132];
  __shared__ float sC[64][132];
  __shared__ float wred[4][40];
  const int tid = threadIdx.x;
  const int bi = blockIdx.x >> 3, bj = blockIdx.x & 7;
  for (int idx = tid; idx < 72 * 33; idx += 256) {
    int r = idx / 33, d4 = idx % 33;
    float4 v = {0.f, 0.f, 0.f, 0.f};
    if (d4 < 25) {
      size_t row = (r < 8) ? (size_t)(bi * 8 + r) : (size_t)(N1 + bj * 64 + (r - 8));
      const float* base = pp + row * DD;
      float4 a0 = ((const float4*)base)[d4];
      float4 a1 = ((const float4*)(base + 102400))[d4];
      float4 a2 = ((const float4*)(base + 204800))[d4];
      float4 a3 = ((const float4*)(base + 307200))[d4];
      float4 bb = ((const float4*)b1)[d4];
      v.x = a0.x + a1.x + a2.x + a3.x + bb.x;
      v.y = a0.y + a1.y + a2.y + a3.y + bb.y;
      v.z = a0.z + a1.z + a2.z + a3.z + bb.z;
      v.w = a0.w + a1.w + a2.w + a3.w + bb.w;
    }
    if (r < 8) *(float4*)&sA[r][4 * d4] = v;
    else       *(float4*)&sC[r - 8][4 * d4] = v;
  }
  __syncthreads();
  const int w = tid >> 6, lane = tid & 63;
  const int ln = lane & 15, q = lane >> 4;
  const int jj = w * 16 + ln;
  bf16x8 af[7][2];
#pragma unroll
  for (int ks = 0; ks < 7; ++ks)
#pragma unroll
    for (int t = 0; t < 2; ++t) {
      bf16x8 v;
#pragma unroll
      for (int e = 0; e < 8; ++e)
        v[e] = (short)w2b[(ks * 32 + q * 8 + e) * 32 + ln + 16 * t];
      af[ks][t] = v;
    }
  int dOf[14];
  bool isP[14];
  float4 cH[14];
#pragma unroll
  for (int hx = 0; hx < 14; ++hx) {
    int kk = (hx >> 1) * 32 + q * 8 + (hx & 1) * 4;
    isP[hx] = kk >= 100;
    dOf[hx] = isP[hx] ? kk - 100 : kk;
    cH[hx] = *(const float4*)&sC[jj][dOf[hx]];
  }
  float st_s[8], st_q[8];
#pragma unroll
  for (int r = 0; r < 8; ++r) { st_s[r] = 0.f; st_q[r] = 0.f; }
  const int gj = bj * 64 + jj;
#pragma unroll 1
  for (int ii = 0; ii < 8; ++ii) {
    bf16x8 bf[7];
#pragma unroll
    for (int ks = 0; ks < 7; ++ks) {
      float4 a0 = *(const float4*)&sA[ii][dOf[2 * ks]];
      float4 a1 = *(const float4*)&sA[ii][dOf[2 * ks + 1]];
      float4 c0 = cH[2 * ks], c1 = cH[2 * ks + 1];
      float f0 = isP[2*ks]   ? a0.x * c0.x : fabsf(a0.x - c0.x);
      float f1 = isP[2*ks]   ? a0.y * c0.y : fabsf(a0.y - c0.y);
      float f2 = isP[2*ks]   ? a0.z * c0.z : fabsf(a0.z - c0.z);
      float f3 = isP[2*ks]   ? a0.w * c0.w : fabsf(a0.w - c0.w);
      float f4 = isP[2*ks+1] ? a1.x * c1.x : fabsf(a1.x - c1.x);
      float f5 = isP[2*ks+1] ? a1.y * c1.y : fabsf(a1.y - c1.y);
      float f6 = isP[2*ks+1] ? a1.z * c1.z : fabsf(a1.z - c1.z);
      float f7 = isP[2*ks+1] ? a1.w * c1.w : fabsf(a1.w - c1.w);
      union { bf16x8 v; __hip_bfloat162 h2[4]; } u;
      u.h2[0] = __float22bfloat162_rn(make_float2(f0, f1));
      u.h2[1] = __float22bfloat162_rn(make_float2(f2, f3));
      u.h2[2] = __float22bfloat162_rn(make_float2(f4, f5));
      u.h2[3] = __float22bfloat162_rn(make_float2(f6, f7));
      bf[ks] = u.v;
    }
    f32x4 acc0 = {0.f, 0.f, 0.f, 0.f}, acc1 = {0.f, 0.f, 0.f, 0.f};
#pragma unroll
    for (int ks = 0; ks < 7; ++ks) {
      acc0 = __builtin_amdgcn_mfma_f32_16x16x32_bf16(af[ks][0], bf[ks], acc0, 0, 0, 0);
      acc1 = __builtin_amdgcn_mfma_f32_16x16x32_bf16(af[ks][1], bf[ks], acc1, 0, 0, 0);
    }
    const size_t pix = (size_t)(bi * 8 + ii) * N2 + gj;
#pragma unroll
    for (int r = 0; r < 4; ++r) {
      m[(size_t)(4 * q + r) * NPIX + pix] = acc0[r];
      st_s[r] += acc0[r];
      st_q[r] += acc0[r] * acc0[r];
    }
    if (q == 0) {
#pragma unroll
      for (int r = 0; r < 4; ++r)
        m[(size_t)(16 + r) * NPIX + pix] = acc1[r];
    }
#pragma unroll
    for (int r = 0; r < 4; ++r) {
      st_s[4 + r] += acc1[r];
      st_q[4 + r] += acc1[r] * acc1[r];
    }
  }
#pragma unroll
  for (int r = 0; r < 8; ++r) {
#pragma unroll
    for (int off = 1; off < 16; off <<= 1) {
      st_s[r] += __shfl_xor(st_s[r], off);
      st_q[r] += __shfl_xor(st_q[r], off);
    }
  }
  if (ln == 0) {
#pragma unroll
    for (int r = 0; r < 4; ++r) {
      wred[w][4 * q + r]      = st_s[r];
      wred[w][20 + 4 * q + r] = st_q[r];
    }
    if (q == 0) {
#pragma unroll
      for (int r = 0; r < 4; ++r) {
        wred[w][16 + r] = st_s[4 + r];
        wred[w][36 + r] = st_q[4 + r];
      }
    }
  }
  __syncthreads();
  if (tid < 40)
    atomicAdd(&stats[tid], wred[0][tid] + wred[1][tid] + wred[2][tid] + wred[3][tid]);
}

// ---- conv 7x7, 20ch, 16x32 tiles (512 blocks = 2/CU), dbuf, 2x1 out/thread
__global__ __launch_bounds__(256, 2) void kD(const float* __restrict__ m,
                                             const float* __restrict__ bn1g,
                                             const float* __restrict__ bn1b,
                                             const float* __restrict__ cw,
                                             float* __restrict__ stats,
                                             float* __restrict__ Craw) {
  __shared__ float sIn[2][4][22][40];
  __shared__ float sSc[HH], sSh[HH];
  __shared__ float wsum[4][2];
  const int tid = threadIdx.x;
  if (tid < HH) {
    float s = stats[tid], q = stats[HH + tid];
    float mu = s * (1.0f / NPIX);
    float var = q * (1.0f / NPIX) - mu * mu;
    float g = bn1g[tid] / sqrtf(var + 1e-5f);
    sSc[tid] = g;
    sSh[tid] = bn1b[tid] - mu * g;
  }
  const int by = (blockIdx.x >> 4) * 16, bx = (blockIdx.x & 15) * 32;
  const int w = tid >> 6, lane = tid & 63;
  const int gxs = bx + lane - 4;
  const bool colOk = (lane < 40) && (gxs >= 0) && (gxs < N2);
  float ld[22];
  {   // prologue: chunk 0 (wave w = channel w)
    const float* mp = m + (size_t)w * NPIX + gxs;
#pragma unroll
    for (int r = 0; r < 22; ++r) {
      int gy = by + r - 3;
      ld[r] = (colOk && gy >= 0 && gy < N1) ? mp[(size_t)gy * N2] : 0.0f;
    }
  }
  __syncthreads();   // sSc/sSh ready
  if (lane < 40) {
    float sc = sSc[w], sh = sSh[w];
#pragma unroll
    for (int r = 0; r < 22; ++r) {
      int gy = by + r - 3;
      bool ok = colOk && gy >= 0 && gy < N1;
      sIn[0][w][r][lane] = ok ? fmaxf(fmaf(ld[r], sc, sh), 0.0f) : 0.0f;
    }
  }
  __syncthreads();
  const int ty = tid >> 4, tx = tid & 15;   // output row ty, col pair tx
  float acc00 = 0.f, acc01 = 0.f;
#pragma unroll 1
  for (int cc = 0; cc < 5; ++cc) {
    if (cc < 4) {   // issue next chunk's loads early
      const float* mp = m + (size_t)((cc + 1) * 4 + w) * NPIX + gxs;
#pragma unroll
      for (int r = 0; r < 22; ++r) {
        int gy = by + r - 3;
        ld[r] = (colOk && gy >= 0 && gy < N1) ? mp[(size_t)gy * N2] : 0.0f;
      }
    }
    const int cur = cc & 1;
#pragma unroll 1
    for (int ch4 = 0; ch4 < 4; ++ch4) {
      float2 win[7][5];   // rows ty..ty+6, cols 2tx..2tx+9
#pragma unroll
      for (int rr = 0; rr < 7; ++rr)
#pragma unroll
        for (int qq = 0; qq < 5; ++qq)
          win[rr][qq] = *(const float2*)&sIn[cur][ch4][ty + rr][2 * tx + 2 * qq];
      const float* wch = cw + (cc * 4 + ch4) * 49;   // uniform -> s_load
#pragma unroll
      for (int ky = 0; ky < 7; ++ky)
#pragma unroll
        for (int kx = 0; kx < 7; ++kx) {
          float wt = wch[ky * 7 + kx];
          float e0 = ((kx + 1) & 1) ? win[ky][(kx + 1) >> 1].y : win[ky][(kx + 1) >> 1].x;
          float e1 = ((kx + 2) & 1) ? win[ky][(kx + 2) >> 1].y : win[ky][(kx + 2) >> 1].x;
          acc00 = fmaf(e0, wt, acc00);
          acc01 = fmaf(e1, wt, acc01);
        }
    }
    __syncthreads();
    if (cc < 4 && lane < 40) {
      int ch = (cc + 1) * 4 + w;
      float sc = sSc[ch], sh = sSh[ch];
#pragma unroll
      for (int r = 0; r < 22; ++r) {
        int gy = by + r - 3;
        bool ok = colOk && gy >= 0 && gy < N1;
        sIn[cur ^ 1][w][r][lane] = ok ? fmaxf(fmaf(ld[r], sc, sh), 0.0f) : 0.0f;
      }
    }
    __syncthreads();
  }
  const int oy = by + ty, ox = bx + 2 * tx;
  float2 r0 = {acc00, acc01};
  *(float2*)&Craw[(size_t)oy * N2 + ox] = r0;
  float s = acc00 + acc01;
  float q = acc00 * acc00 + acc01 * acc01;
#pragma unroll
  for (int off = 32; off; off >>= 1) {
    s += __shfl_xor(s, off);
    q += __shfl_xor(q, off);
  }
  if (lane == 0) { wsum[w][0] = s; wsum[w][1] = q; }
  __syncthreads();
  if (tid < 2) {
    float v = wsum[0][tid] + wsum[1][tid] + wsum[2][tid] + wsum[3][tid];
    atomicAdd(&stats[2 * HH + tid], v);
  }
}

// ---- fused BN2 + sigmoid + maxpool: one wave per 9x9 window
__global__ __launch_bounds__(256) void kE2M(const float* __restrict__ Craw,
                                            const float* __restrict__ stats,
                                            const float* __restrict__ bn2g,
                                            const float* __restrict__ bn2b,
                                            float* __restrict__ Cout,
                                            float* __restrict__ B) {
  const int w = blockIdx.x * 4 + (threadIdx.x >> 6);
  const int lane = threadIdx.x & 63;
  float s = stats[2 * HH], q = stats[2 * HH + 1];
  float mu = s * (1.0f / NPIX);
  float var = q * (1.0f / NPIX) - mu * mu;
  float g = bn2g[0] / sqrtf(var + 1e-5f);
  float b = bn2b[0] - mu * g;
  if (w >= PB * PB) return;
  const int wy = w / PB, wx = w % PB;
  const int y0 = wy * 9 - 4, x0 = wx * 9 - 4;
  float mx = -1e30f;
  for (int e = lane; e < 144; e += 64) {
    int dy = e / 12, dx = e % 12;
    int y = y0 + dy, x = x0 + dx;
    bool inWin = (dy < 9) && (dx < 9);
    bool claim = (y >= 0) && (y < N1) && (x >= 0) && (x < N2) &&
                 (dy < 9 || wy == PB - 1) && (dx < 9 || wx == PB - 1);
    if (claim) {
      float z = Craw[(size_t)y * N2 + x] * g + b;
      float sg = 1.0f / (1.0f + expf(-z));
      Cout[(size_t)y * N2 + x] = sg;
      if (inWin) mx = fmaxf(mx, sg);
    }
  }
#pragma unroll
  for (int off = 32; off; off >>= 1) mx = fmaxf(mx, __shfl_xor(mx, off));
  if (lane == 0) B[w] = mx;
}

// ---- per-column mean/std(ddof=1), phat -> d_out[0]
__global__ __launch_bounds__(1024) void kF(const float* __restrict__ B,
                                           const float* __restrict__ gamma,
                                           float* __restrict__ out0) {
  __shared__ float sB[PB * PB];
  __shared__ float cm[PB], cs[PB];
  __shared__ float r1[16], r2[16];
  const int tid = threadIdx.x;
  for (int i = tid; i < PB * PB; i += 1024) sB[i] = B[i];
  __syncthreads();
  if (tid < PB * 16) {
    int c = tid >> 4, g = tid & 15;
    float s = 0.0f;
    for (int h = g; h < PB; h += 16) s += sB[h * PB + c];
#pragma unroll
    for (int off = 1; off < 16; off <<= 1) s += __shfl_xor(s, off);
    float mean = s / (float)PB;
    float v = 0.0f;
    for (int h = g; h < PB; h += 16) { float d = sB[h * PB + c] - mean; v += d * d; }
#pragma unroll
    for (int off = 1; off < 16; off <<= 1) v += __shfl_xor(v, off);
    if (g == 0) {
      cm[c] = mean;
      cs[c] = sqrtf(v / (float)(PB - 1) + 1e-5f);
    }
  }
  __syncthreads();
  const float g = gamma[0];
  float sq = 0.0f, cnt = 0.0f;
  for (int i = tid; i < PB * PB; i += 1024) {
    int w = i % PB;
    float qv = sB[i] - cm[w] - g * cs[w];
    if (qv > 0.0f) { sq += qv; cnt += 1.0f; }
  }
#pragma unroll
  for (int off = 32; off; off >>= 1) {
    sq += __shfl_xor(sq, off);
    cnt += __shfl_xor(cnt, off);
  }
  if ((tid & 63) == 0) { r1[tid >> 6] = sq; r2[tid >> 6] = cnt; }
  __syncthreads();
  if (tid == 0) {
    float S = 0.f, Cn = 0.f;
#pragma unroll
    for (int e = 0; e < 16; ++e) { S += r1[e]; Cn += r2[e]; }
    float phat = S / (Cn + 1.0f);
    float sig = 1.0f / (1.0f + expf(-phat));
    out0[0] = fminf(fmaxf(sig, 0.0f), 1.0f);
  }
}

extern "C" void kernel_launch(void* const* d_in, const int* in_sizes, int n_in,
                              void* d_out, int out_size, void* d_ws, size_t ws_size,
                              hipStream_t stream) {
  const float* x1    = (const float*)d_in[0];
  const float* x2    = (const float*)d_in[1];
  const float* W1    = (const float*)d_in[2];
  const float* b1    = (const float*)d_in[3];
  const float* W2    = (const float*)d_in[4];
  // d_in[5] = b2   : cancels through BN1 (training-mode mean subtraction)
  const float* bn1g  = (const float*)d_in[6];
  const float* bn1b  = (const float*)d_in[7];
  const float* convw = (const float*)d_in[8];
  // d_in[9] = conv_b : cancels through BN2
  const float* bn2g  = (const float*)d_in[10];
  const float* bn2b  = (const float*)d_in[11];
  const float* gamma = (const float*)d_in[12];

  float* ws    = (float*)d_ws;
  float* pp    = ws + WS_PP;
  float* w1t   = ws + WS_W1T;
  unsigned short* w2b = (unsigned short*)(ws + WS_W2B);
  float* m     = ws + WS_M;
  float* Craw  = ws + WS_CRAW;
  float* stats = ws + WS_STATS;
  float* Bp    = ws + WS_B;
  float* out   = (float*)d_out;

  kP<<<188, 256, 0, stream>>>(W1, W2, w1t, w2b, stats);
  kA<<<1024, 256, 0, stream>>>(x1, x2, w1t, pp);
  kB<<<512, 256, 0, stream>>>(pp, b1, w2b, m, stats);
  kD<<<512, 256, 0, stream>>>(m, bn1g, bn1b, convw, stats, Craw);
  kE2M<<<(PB * PB + 3) / 4, 256, 0, stream>>>(Craw, stats, bn2g, bn2b, out + 1, Bp);
  kF<<<1, 1024, 0, stream>>>(Bp, gamma, out);
}